// Round 4
// baseline (2393.699 us; speedup 1.0000x reference)
//
#include <hip/hip_runtime.h>
#include <stdint.h>

typedef unsigned int uint;

// B=2, N=5120, F=10240, H=W=256. Bit-exact fp32 replication of the reference
// (contract off, IEEE div). Pipeline:
//   transform -> per-face records -> bucket-sort faces by zmin (4096 buckets)
//   -> per-row block (256 thr) scans faces in ascending-zmin order, CHUNK=128
//      LDS-staged (R2's 0-conflict pattern), block-uniform early termination
//      via __syncthreads_and(lb >= bestz+TOL) -> fused bilinear sample.
// Winner = lexicographic (z, orig_f) min == reference chunked argmin.
// Record = 4 float4: q0={xmin,xmax,ymin,ymax} q1={v0x,v0y,e1x,e1y}
//                    q2={e2x,e2y,inv,z0}      q3={z1,z2,bits(orig_f),lb}

#define K_BUCKETS 4096
#define ZLO 0.0f
#define ZHI 20.0f
#define TOL 1e-3f
#define CHUNK 128

__device__ __forceinline__ float clip11(float t) {
  return fminf(1.0f, fmaxf(-1.0f, t));
}

__global__ void k_zero(uint* __restrict__ p, int n) {
  int t = blockIdx.x * 256 + threadIdx.x;
  if (t < n) p[t] = 0u;
}

__global__ void k_transform(const float* __restrict__ hv,
                            const float* __restrict__ cam,
                            const float* __restrict__ camn,
                            float* __restrict__ pos,   // B*N*4
                            float* __restrict__ uv,    // B*N*2
                            int N, int B) {
#pragma clang fp contract(off)
  int t = blockIdx.x * 256 + threadIdx.x;
  if (t >= B * N) return;
  int b = t / N;
  float X0 = hv[t * 3 + 0];
  float X1 = hv[t * 3 + 1];
  float X2 = hv[t * 3 + 2];
  {
    float c0 = camn[b * 3 + 0], c1 = camn[b * 3 + 1], c2 = camn[b * 3 + 2];
    float t0 = c0 * (X0 + c1);
    float t1 = c0 * (X1 + c2);
    float t2 = c0 * X2;
    pos[t * 4 + 0] = clip11(t0);
    pos[t * 4 + 1] = clip11(-t1);
    pos[t * 4 + 2] = -t2 + 10.0f;
    pos[t * 4 + 3] = 0.0f;
  }
  {
    float c0 = cam[b * 3 + 0], c1 = cam[b * 3 + 1], c2 = cam[b * 3 + 2];
    float t0 = c0 * (X0 + c1);
    float t1 = c0 * (X1 + c2);
    uv[t * 2 + 0] = clip11(t0);
    uv[t * 2 + 1] = clip11(-t1);
  }
}

__global__ void k_faces(const int* __restrict__ faces,
                        const float* __restrict__ pos,
                        const float* __restrict__ uv,
                        float4* __restrict__ fh4,   // B*F*4 (orig order)
                        float4* __restrict__ fa4,   // B*F*2 (orig order)
                        uint* __restrict__ bkt,     // B*F
                        uint* __restrict__ cnt,     // B*K
                        int F, int N, int B) {
#pragma clang fp contract(off)
  int t = blockIdx.x * 256 + threadIdx.x;
  if (t >= B * F) return;
  int b = t / F;
  int f = t - b * F;
  int i0 = faces[f * 3 + 0];
  int i1 = faces[f * 3 + 1];
  int i2 = faces[f * 3 + 2];
  const float* p0 = pos + (size_t)(b * N + i0) * 4;
  const float* p1 = pos + (size_t)(b * N + i1) * 4;
  const float* p2 = pos + (size_t)(b * N + i2) * 4;
  float x0 = p0[0], y0 = p0[1], z0 = p0[2];
  float x1 = p1[0], y1 = p1[1], z1 = p1[2];
  float x2 = p2[0], y2 = p2[1], z2 = p2[2];
  float e1x = x1 - x0;
  float e1y = y1 - y0;
  float e2x = x2 - x0;
  float e2y = y2 - y0;
  float d = (e1x * e2y) - (e2x * e1y);
  float inv;
  if (fabsf(d) > 1e-8f) {
    inv = 1.0f / d;                     // IEEE division
  } else {
    inv = __int_as_float(0x7fc00000);   // NaN -> inside test fails
  }
  float4* fq = fh4 + (size_t)t * 4;
  fq[0] = make_float4(fminf(x0, fminf(x1, x2)), fmaxf(x0, fmaxf(x1, x2)),
                      fminf(y0, fminf(y1, y2)), fmaxf(y0, fmaxf(y1, y2)));
  fq[1] = make_float4(x0, y0, e1x, e1y);
  fq[2] = make_float4(e2x, e2y, inv, z0);
  fq[3] = make_float4(z1, z2, 0.0f, 0.0f);

  float zmn = fminf(z0, fminf(z1, z2));
  int kb = (int)((zmn - ZLO) * ((float)K_BUCKETS / (ZHI - ZLO)));
  kb = min(max(kb, 0), K_BUCKETS - 1);
  bkt[t] = (uint)kb;
  atomicAdd(&cnt[b * K_BUCKETS + kb], 1u);

  float u0 = uv[(size_t)(b * N + i0) * 2 + 0];
  float v0 = uv[(size_t)(b * N + i0) * 2 + 1];
  float u1 = uv[(size_t)(b * N + i1) * 2 + 0];
  float v1 = uv[(size_t)(b * N + i1) * 2 + 1];
  float u2 = uv[(size_t)(b * N + i2) * 2 + 0];
  float v2 = uv[(size_t)(b * N + i2) * 2 + 1];
  float4* aq = fa4 + (size_t)t * 2;
  aq[0] = make_float4(u0, v0, u1, v1);
  aq[1] = make_float4(u2, v2, 0.0f, 0.0f);
}

// one block per batch; exclusive prefix over K_BUCKETS counts
__global__ void __launch_bounds__(1024) k_prefix(const uint* __restrict__ cnt,
                                                 uint* __restrict__ off) {
  __shared__ uint s[1024];
  int b = blockIdx.x;
  const uint* c = cnt + (size_t)b * K_BUCKETS;
  uint* o = off + (size_t)b * K_BUCKETS;
  int tid = threadIdx.x;
  uint v0 = c[tid * 4 + 0], v1 = c[tid * 4 + 1], v2 = c[tid * 4 + 2], v3 = c[tid * 4 + 3];
  uint sum = v0 + v1 + v2 + v3;
  s[tid] = sum;
  __syncthreads();
  for (int d = 1; d < 1024; d <<= 1) {
    uint t = (tid >= d) ? s[tid - d] : 0u;
    __syncthreads();
    s[tid] += t;
    __syncthreads();
  }
  uint run = s[tid] - sum;   // exclusive
  o[tid * 4 + 0] = run; run += v0;
  o[tid * 4 + 1] = run; run += v1;
  o[tid * 4 + 2] = run; run += v2;
  o[tid * 4 + 3] = run;
}

__global__ void k_scatter(const float4* __restrict__ fh4,
                          const uint* __restrict__ bkt,
                          uint* __restrict__ off,       // consumed as cursor
                          float4* __restrict__ srec,    // B*F*4 sorted
                          int F, int B) {
  int t = blockIdx.x * 256 + threadIdx.x;
  if (t >= B * F) return;
  int b = t / F;
  int f = t - b * F;
  uint kb = bkt[t];
  uint pos = atomicAdd(&off[b * K_BUCKETS + kb], 1u);
  const float4* s = fh4 + (size_t)t * 4;
  float4 q0 = s[0], q1 = s[1], q2 = s[2], q3 = s[3];
  q3.z = __uint_as_float((uint)f);
  q3.w = (kb == 0u) ? -1e30f : (ZLO + (float)kb * ((ZHI - ZLO) / (float)K_BUCKETS));
  float4* d = srec + ((size_t)b * F + pos) * 4;
  d[0] = q0; d[1] = q1; d[2] = q2; d[3] = q3;
}

// per-chunk z lower bound: lb of the first sorted face of each chunk
__global__ void k_lb(const float4* __restrict__ srec,
                     float* __restrict__ lbArr,
                     int F, int NCH, int B) {
  int t = blockIdx.x * 256 + threadIdx.x;
  if (t >= B * NCH) return;
  int b = t / NCH;
  int c = t - b * NCH;
  int fi = c * CHUNK;
  if (fi >= F) { lbArr[t] = 1e30f; return; }
  lbArr[t] = srec[((size_t)b * F + fi) * 4 + 3].w;
}

__device__ __forceinline__ float fetchpix(const float* __restrict__ img, int base,
                                          float ixf, float iyf) {
  bool valid = (ixf >= 0.0f) && (ixf < 256.0f) && (iyf >= 0.0f) && (iyf < 256.0f);
  int ix = (int)fminf(255.0f, fmaxf(0.0f, ixf));
  int iy = (int)fminf(255.0f, fmaxf(0.0f, iyf));
  float v = img[base + iy * 256 + ix];
  return valid ? v : 0.0f;
}

// one block (256 thr = 4 waves) per row; grid = B*256 blocks
__global__ void __launch_bounds__(256) k_raster(const float4* __restrict__ srec,
                                                const float4* __restrict__ fa4,
                                                const float* __restrict__ lbArr,
                                                const float* __restrict__ img,
                                                float* __restrict__ out,
                                                int F, int NCH) {
#pragma clang fp contract(off)
  int blk = blockIdx.x;           // b*256 + row
  int row = blk & 255;
  int b = blk >> 8;
  int tid = threadIdx.x;
  int col = tid;

  float px = (col + 0.5f) / 256.0f * 2.0f - 1.0f;
  float py = (row + 0.5f) / 256.0f * 2.0f - 1.0f;          // wave-uniform
  int wv = tid >> 6;
  float pxlo = (wv * 64 + 0.5f) / 256.0f * 2.0f - 1.0f;    // wave-uniform
  float pxhi = (wv * 64 + 63 + 0.5f) / 256.0f * 2.0f - 1.0f;

  const float4* __restrict__ base4 = srec + (size_t)b * F * 4;
  const float* __restrict__ lbB = lbArr + (size_t)b * NCH;
  __shared__ float4 lds[CHUNK * 4];

  float bestz = 1000000.0f;
  uint bestfo = 0xFFFFFFFFu;
  float bw0 = 0.0f, bw1 = 0.0f, bw2 = 0.0f;

  int total4 = F * 4;
  // prefetch chunk 0 (R2 pattern: elements tid and tid+256, stride-16B lanes)
  float4 r0, r1;
  {
    if (tid < total4)       r0 = base4[tid];
    if (tid + 256 < total4) r1 = base4[tid + 256];
  }

  for (int cb = 0; cb < F; cb += CHUNK) {
    int nf = min(CHUNK, F - cb);
    float lb = lbB[cb >> 7];   // CHUNK == 128
    // block-uniform early termination; also serves as LDS-overwrite guard
    if (__syncthreads_and(lb >= bestz + TOL)) break;
    {
      int n4 = nf * 4;
      if (tid < n4)       lds[tid]       = r0;
      if (tid + 256 < n4) lds[tid + 256] = r1;
    }
    __syncthreads();
    // issue next-chunk prefetch early
    int nb = cb + CHUNK;
    if (nb < F) {
      int e0 = nb * 4 + tid;
      if (e0 < total4)       r0 = base4[e0];
      if (e0 + 256 < total4) r1 = base4[e0 + 256];
    }
    for (int k = 0; k < nf; ++k) {
      float4 q0 = lds[k * 4 + 0];
      // wave-uniform conservative bbox cull
      if (!(q0.z <= py && q0.w >= py && q0.x <= pxhi && q0.y >= pxlo))
        continue;
      float4 q1 = lds[k * 4 + 1];
      float4 q2 = lds[k * 4 + 2];
      float dpx = px - q1.x;
      float dpy = py - q1.y;
      float w1 = (dpx * q2.y - q2.x * dpy) * q2.z;
      float w2 = (q1.z * dpy - dpx * q1.w) * q2.z;
      float w0 = (1.0f - w1) - w2;
      if (w0 >= 0.0f && w1 >= 0.0f && w2 >= 0.0f) {
        float4 q3 = lds[k * 4 + 3];
        float z = (w0 * q2.w + w1 * q3.x) + w2 * q3.y;
        uint fo = __float_as_uint(q3.z);
        // lexicographic (z, orig_f): deterministic, matches ref tie-break
        if (z < bestz || (z == bestz && fo < bestfo)) {
          bestz = z;
          bestfo = fo;
          bw0 = w0; bw1 = w1; bw2 = w2;
        }
      }
    }
  }

  float gx = 0.0f, gy = 0.0f;
  if (bestfo != 0xFFFFFFFFu) {
    const float4* aq = fa4 + ((size_t)b * F + bestfo) * 2;
    float4 a0 = aq[0];
    float4 a1 = aq[1];
    gx = (bw0 * a0.x + bw1 * a0.z) + bw2 * a1.x;
    gy = (bw0 * a0.y + bw1 * a0.w) + bw2 * a1.y;
  }

  // grid_sample (align_corners=False, zero pad), exact ref op order
  float x = (gx + 1.0f) * 0.5f * 256.0f - 0.5f;
  float y = (gy + 1.0f) * 0.5f * 256.0f - 0.5f;
  float x0f = floorf(x), y0f = floorf(y);
  float wx1 = x - x0f, wx0 = 1.0f - wx1;
  float wy1 = y - y0f, wy0 = 1.0f - wy1;

  int pix = row * 256 + col;
  for (int c = 0; c < 3; ++c) {
    int base = (b * 3 + c) * 65536;
    float f00 = fetchpix(img, base, x0f, y0f);
    float f10 = fetchpix(img, base, x0f + 1.0f, y0f);
    float f01 = fetchpix(img, base, x0f, y0f + 1.0f);
    float f11 = fetchpix(img, base, x0f + 1.0f, y0f + 1.0f);
    float A  = wy0 * ((wx0 * f00) + (wx1 * f10));
    float Bv = wy1 * ((wx0 * f01) + (wx1 * f11));
    out[base + pix] = A + Bv;
  }
}

extern "C" void kernel_launch(void* const* d_in, const int* in_sizes, int n_in,
                              void* d_out, int out_size, void* d_ws, size_t ws_size,
                              hipStream_t stream) {
  const float* cam  = (const float*)d_in[0];
  const float* hv   = (const float*)d_in[1];
  const float* img  = (const float*)d_in[2];
  const float* camn = (const float*)d_in[3];
  const int* faces  = (const int*)d_in[4];

  const int B = in_sizes[0] / 3;            // 2
  const int N = in_sizes[1] / (3 * B);      // 5120
  const int F = in_sizes[4] / 3;            // 10240
  const int NCH = (F + CHUNK - 1) / CHUNK;  // 80

  char* wsb = (char*)d_ws;
  size_t ofs = 0;
  float* pos = (float*)(wsb + ofs); ofs += (size_t)B * N * 4 * 4;
  float* uv  = (float*)(wsb + ofs); ofs += (size_t)B * N * 2 * 4;
  ofs = (ofs + 255) & ~(size_t)255;
  float4* fh4  = (float4*)(wsb + ofs); ofs += (size_t)B * F * 4 * sizeof(float4);
  float4* fa4  = (float4*)(wsb + ofs); ofs += (size_t)B * F * 2 * sizeof(float4);
  float4* srec = (float4*)(wsb + ofs); ofs += (size_t)B * F * 4 * sizeof(float4);
  uint* bkt = (uint*)(wsb + ofs); ofs += (size_t)B * F * 4;
  uint* cnt = (uint*)(wsb + ofs); ofs += (size_t)B * K_BUCKETS * 4;
  uint* off = (uint*)(wsb + ofs); ofs += (size_t)B * K_BUCKETS * 4;
  float* lbArr = (float*)(wsb + ofs); ofs += (size_t)B * NCH * 4;

  int nz = B * K_BUCKETS;
  k_zero<<<(nz + 255) / 256, 256, 0, stream>>>(cnt, nz);
  int nv = B * N;
  k_transform<<<(nv + 255) / 256, 256, 0, stream>>>(hv, cam, camn, pos, uv, N, B);
  int nf = B * F;
  k_faces<<<(nf + 255) / 256, 256, 0, stream>>>(faces, pos, uv, fh4, fa4, bkt, cnt, F, N, B);
  k_prefix<<<B, 1024, 0, stream>>>(cnt, off);
  k_scatter<<<(nf + 255) / 256, 256, 0, stream>>>(fh4, bkt, off, srec, F, B);
  int nlb = B * NCH;
  k_lb<<<(nlb + 255) / 256, 256, 0, stream>>>(srec, lbArr, F, NCH, B);
  k_raster<<<B * 256, 256, 0, stream>>>(srec, fa4, lbArr, img, (float*)d_out, F, NCH);
}

// Round 5
// 1098.167 us; speedup vs baseline: 2.1797x; 2.1797x over previous
//
#include <hip/hip_runtime.h>
#include <stdint.h>

typedef unsigned int uint;
typedef unsigned long long ull;

// B=2, N=5120, F=10240, H=W=256. Bit-exact fp32 replication of the reference
// (contract off, IEEE div). Pipeline:
//   transform -> per-face records -> bucket-sort faces by zmin (4096 buckets)
//   -> per-16x16-tile block: per 256-face sorted chunk, ballot-compact the
//      faces whose bbox hits the (x-padded) tile into an LDS queue, gather
//      their records, full-test only those; block-uniform early termination
//      via __syncthreads_and(lb >= bestz+TOL) -> fused bilinear sample.
// Winner = lexicographic (z, orig_f) min == reference chunked argmin.
// Record = 4 float4: q0={xmin,xmax,ymin,ymax} q1={v0x,v0y,e1x,e1y}
//                    q2={e2x,e2y,inv,z0}      q3={z1,z2,bits(orig_f),lb}
// Tile x-test padded by 48px (0.375 clip) => queued set is a superset of the
// validated 64px-strip cull of R2 for every pixel of the tile.

#define K_BUCKETS 4096
#define ZLO 0.0f
#define ZHI 20.0f
#define TOL 1e-3f
#define RCH 256          // faces per sorted chunk in raster
#define XPAD 0.375f      // 48px in clip units

__device__ __forceinline__ float clip11(float t) {
  return fminf(1.0f, fmaxf(-1.0f, t));
}

__global__ void k_zero(uint* __restrict__ p, int n) {
  int t = blockIdx.x * 256 + threadIdx.x;
  if (t < n) p[t] = 0u;
}

__global__ void k_transform(const float* __restrict__ hv,
                            const float* __restrict__ cam,
                            const float* __restrict__ camn,
                            float* __restrict__ pos,   // B*N*4
                            float* __restrict__ uv,    // B*N*2
                            int N, int B) {
#pragma clang fp contract(off)
  int t = blockIdx.x * 256 + threadIdx.x;
  if (t >= B * N) return;
  int b = t / N;
  float X0 = hv[t * 3 + 0];
  float X1 = hv[t * 3 + 1];
  float X2 = hv[t * 3 + 2];
  {
    float c0 = camn[b * 3 + 0], c1 = camn[b * 3 + 1], c2 = camn[b * 3 + 2];
    float t0 = c0 * (X0 + c1);
    float t1 = c0 * (X1 + c2);
    float t2 = c0 * X2;
    pos[t * 4 + 0] = clip11(t0);
    pos[t * 4 + 1] = clip11(-t1);
    pos[t * 4 + 2] = -t2 + 10.0f;
    pos[t * 4 + 3] = 0.0f;
  }
  {
    float c0 = cam[b * 3 + 0], c1 = cam[b * 3 + 1], c2 = cam[b * 3 + 2];
    float t0 = c0 * (X0 + c1);
    float t1 = c0 * (X1 + c2);
    uv[t * 2 + 0] = clip11(t0);
    uv[t * 2 + 1] = clip11(-t1);
  }
}

__global__ void k_faces(const int* __restrict__ faces,
                        const float* __restrict__ pos,
                        const float* __restrict__ uv,
                        float4* __restrict__ fh4,   // B*F*4 (orig order)
                        float4* __restrict__ fa4,   // B*F*2 (orig order)
                        uint* __restrict__ bkt,     // B*F
                        uint* __restrict__ cnt,     // B*K
                        int F, int N, int B) {
#pragma clang fp contract(off)
  int t = blockIdx.x * 256 + threadIdx.x;
  if (t >= B * F) return;
  int b = t / F;
  int f = t - b * F;
  int i0 = faces[f * 3 + 0];
  int i1 = faces[f * 3 + 1];
  int i2 = faces[f * 3 + 2];
  const float* p0 = pos + (size_t)(b * N + i0) * 4;
  const float* p1 = pos + (size_t)(b * N + i1) * 4;
  const float* p2 = pos + (size_t)(b * N + i2) * 4;
  float x0 = p0[0], y0 = p0[1], z0 = p0[2];
  float x1 = p1[0], y1 = p1[1], z1 = p1[2];
  float x2 = p2[0], y2 = p2[1], z2 = p2[2];
  float e1x = x1 - x0;
  float e1y = y1 - y0;
  float e2x = x2 - x0;
  float e2y = y2 - y0;
  float d = (e1x * e2y) - (e2x * e1y);
  float inv;
  if (fabsf(d) > 1e-8f) {
    inv = 1.0f / d;                     // IEEE division
  } else {
    inv = __int_as_float(0x7fc00000);   // NaN -> inside test fails
  }
  float4* fq = fh4 + (size_t)t * 4;
  fq[0] = make_float4(fminf(x0, fminf(x1, x2)), fmaxf(x0, fmaxf(x1, x2)),
                      fminf(y0, fminf(y1, y2)), fmaxf(y0, fmaxf(y1, y2)));
  fq[1] = make_float4(x0, y0, e1x, e1y);
  fq[2] = make_float4(e2x, e2y, inv, z0);
  fq[3] = make_float4(z1, z2, 0.0f, 0.0f);

  float zmn = fminf(z0, fminf(z1, z2));
  int kb = (int)((zmn - ZLO) * ((float)K_BUCKETS / (ZHI - ZLO)));
  kb = min(max(kb, 0), K_BUCKETS - 1);
  bkt[t] = (uint)kb;
  atomicAdd(&cnt[b * K_BUCKETS + kb], 1u);

  float u0 = uv[(size_t)(b * N + i0) * 2 + 0];
  float v0 = uv[(size_t)(b * N + i0) * 2 + 1];
  float u1 = uv[(size_t)(b * N + i1) * 2 + 0];
  float v1 = uv[(size_t)(b * N + i1) * 2 + 1];
  float u2 = uv[(size_t)(b * N + i2) * 2 + 0];
  float v2 = uv[(size_t)(b * N + i2) * 2 + 1];
  float4* aq = fa4 + (size_t)t * 2;
  aq[0] = make_float4(u0, v0, u1, v1);
  aq[1] = make_float4(u2, v2, 0.0f, 0.0f);
}

// one block per batch; exclusive prefix over K_BUCKETS counts
__global__ void __launch_bounds__(1024) k_prefix(const uint* __restrict__ cnt,
                                                 uint* __restrict__ off) {
  __shared__ uint s[1024];
  int b = blockIdx.x;
  const uint* c = cnt + (size_t)b * K_BUCKETS;
  uint* o = off + (size_t)b * K_BUCKETS;
  int tid = threadIdx.x;
  uint v0 = c[tid * 4 + 0], v1 = c[tid * 4 + 1], v2 = c[tid * 4 + 2], v3 = c[tid * 4 + 3];
  uint sum = v0 + v1 + v2 + v3;
  s[tid] = sum;
  __syncthreads();
  for (int d = 1; d < 1024; d <<= 1) {
    uint t = (tid >= d) ? s[tid - d] : 0u;
    __syncthreads();
    s[tid] += t;
    __syncthreads();
  }
  uint run = s[tid] - sum;   // exclusive
  o[tid * 4 + 0] = run; run += v0;
  o[tid * 4 + 1] = run; run += v1;
  o[tid * 4 + 2] = run; run += v2;
  o[tid * 4 + 3] = run;
}

__global__ void k_scatter(const float4* __restrict__ fh4,
                          const uint* __restrict__ bkt,
                          uint* __restrict__ off,       // consumed as cursor
                          float4* __restrict__ srec,    // B*F*4 sorted
                          float4* __restrict__ bboxs,   // B*F sorted bboxes
                          int F, int B) {
  int t = blockIdx.x * 256 + threadIdx.x;
  if (t >= B * F) return;
  int b = t / F;
  int f = t - b * F;
  uint kb = bkt[t];
  uint pos = atomicAdd(&off[b * K_BUCKETS + kb], 1u);
  const float4* s = fh4 + (size_t)t * 4;
  float4 q0 = s[0], q1 = s[1], q2 = s[2], q3 = s[3];
  q3.z = __uint_as_float((uint)f);
  q3.w = (kb == 0u) ? -1e30f : (ZLO + (float)kb * ((ZHI - ZLO) / (float)K_BUCKETS));
  float4* d = srec + ((size_t)b * F + pos) * 4;
  d[0] = q0; d[1] = q1; d[2] = q2; d[3] = q3;
  bboxs[(size_t)b * F + pos] = q0;
}

// per-chunk z lower bound: lb of the first sorted face of each RCH-chunk
__global__ void k_lb(const float4* __restrict__ srec,
                     float* __restrict__ lbC,
                     int F, int NCHC, int B) {
  int t = blockIdx.x * 256 + threadIdx.x;
  if (t >= B * NCHC) return;
  int b = t / NCHC;
  int ch = t - b * NCHC;
  int fi = ch * RCH;
  if (fi >= F) { lbC[t] = 1e30f; return; }
  lbC[t] = srec[((size_t)b * F + fi) * 4 + 3].w;
}

__device__ __forceinline__ float fetchpix(const float* __restrict__ img, int base,
                                          float ixf, float iyf) {
  bool valid = (ixf >= 0.0f) && (ixf < 256.0f) && (iyf >= 0.0f) && (iyf < 256.0f);
  int ix = (int)fminf(255.0f, fmaxf(0.0f, ixf));
  int iy = (int)fminf(255.0f, fmaxf(0.0f, iyf));
  float v = img[base + iy * 256 + ix];
  return valid ? v : 0.0f;
}

// one block (256 thr) per 16x16 pixel tile; grid = B*256 blocks
__global__ void __launch_bounds__(256) k_raster(const float4* __restrict__ srec,
                                                const float4* __restrict__ fa4,
                                                const float4* __restrict__ bboxs,
                                                const float* __restrict__ lbC,
                                                const float* __restrict__ img,
                                                float* __restrict__ out,
                                                int F, int NCHC) {
#pragma clang fp contract(off)
  int blk = blockIdx.x;           // b*256 + tile
  int tile = blk & 255;
  int b = blk >> 8;
  int tx = tile & 15, ty = tile >> 4;
  int tid = threadIdx.x;
  int c = tid & 15, r = tid >> 4;
  int col = tx * 16 + c;
  int row = ty * 16 + r;

  float px = (col + 0.5f) / 256.0f * 2.0f - 1.0f;
  float py = (row + 0.5f) / 256.0f * 2.0f - 1.0f;
  float txlo = (tx * 16 + 0.5f) / 256.0f * 2.0f - 1.0f - XPAD;
  float txhi = (tx * 16 + 15.5f) / 256.0f * 2.0f - 1.0f + XPAD;
  float tylo = (ty * 16 + 0.5f) / 256.0f * 2.0f - 1.0f;
  float tyhi = (ty * 16 + 15.5f) / 256.0f * 2.0f - 1.0f;

  const float4* __restrict__ srecB = srec + (size_t)b * F * 4;
  const float4* __restrict__ bbB = bboxs + (size_t)b * F;
  const float* __restrict__ lbB = lbC + b * NCHC;

  __shared__ float4 recs[RCH * 4];   // 16 KB
  __shared__ uint qs[RCH];
  __shared__ uint wcnt[4];

  float bestz = 1000000.0f;
  uint bestfo = 0xFFFFFFFFu;
  float bw0 = 0.0f, bw1 = 0.0f, bw2 = 0.0f;

  for (int cb = 0; cb < F; cb += RCH) {
    // block-uniform early termination; also the LDS reuse guard barrier
    if (__syncthreads_and((int)(lbB[cb >> 8] >= bestz + TOL))) break;

    int si = cb + tid;
    bool ok = false;
    if (si < F) {
      float4 bb = bbB[si];   // coalesced
      ok = (bb.x <= txhi && bb.y >= txlo && bb.z <= tyhi && bb.w >= tylo);
    }
    ull m = __ballot(ok);
    int lane = tid & 63, wv = tid >> 6;
    if (lane == 0) wcnt[wv] = (uint)__popcll(m);
    int rank = (int)__popcll(m & ((1ull << lane) - 1ull));
    __syncthreads();
    int woff = 0;
#pragma unroll
    for (int w = 0; w < 4; ++w)
      if (w < wv) woff += (int)wcnt[w];
    int nq = (int)(wcnt[0] + wcnt[1] + wcnt[2] + wcnt[3]);
    if (ok) qs[woff + rank] = (uint)si;   // order-preserving (ascending si)
    __syncthreads();
    // cooperative gather of full records (64B per face, L2-resident)
    for (int idx = tid; idx < nq * 4; idx += 256)
      recs[idx] = srecB[(size_t)qs[idx >> 2] * 4 + (idx & 3)];
    __syncthreads();
    for (int k = 0; k < nq; ++k) {
      float4 q0 = recs[k * 4 + 0];          // LDS broadcast (uniform k)
      if (!(q0.z <= py && q0.w >= py)) continue;   // exact-row y cull (validated)
      float4 q1 = recs[k * 4 + 1];
      float4 q2 = recs[k * 4 + 2];
      float dpx = px - q1.x;
      float dpy = py - q1.y;
      float w1 = (dpx * q2.y - q2.x * dpy) * q2.z;
      float w2 = (q1.z * dpy - dpx * q1.w) * q2.z;
      float w0 = (1.0f - w1) - w2;
      if (w0 >= 0.0f && w1 >= 0.0f && w2 >= 0.0f) {
        float4 q3 = recs[k * 4 + 3];
        float z = (w0 * q2.w + w1 * q3.x) + w2 * q3.y;
        uint fo = __float_as_uint(q3.z);
        // lexicographic (z, orig_f): deterministic, matches ref tie-break
        if (z < bestz || (z == bestz && fo < bestfo)) {
          bestz = z;
          bestfo = fo;
          bw0 = w0; bw1 = w1; bw2 = w2;
        }
      }
    }
  }

  float gx = 0.0f, gy = 0.0f;
  if (bestfo != 0xFFFFFFFFu) {
    const float4* aq = fa4 + ((size_t)b * F + bestfo) * 2;
    float4 a0 = aq[0];
    float4 a1 = aq[1];
    gx = (bw0 * a0.x + bw1 * a0.z) + bw2 * a1.x;
    gy = (bw0 * a0.y + bw1 * a0.w) + bw2 * a1.y;
  }

  // grid_sample (align_corners=False, zero pad), exact ref op order
  float x = (gx + 1.0f) * 0.5f * 256.0f - 0.5f;
  float y = (gy + 1.0f) * 0.5f * 256.0f - 0.5f;
  float x0f = floorf(x), y0f = floorf(y);
  float wx1 = x - x0f, wx0 = 1.0f - wx1;
  float wy1 = y - y0f, wy0 = 1.0f - wy1;

  int pix = row * 256 + col;
  for (int ch = 0; ch < 3; ++ch) {
    int base = (b * 3 + ch) * 65536;
    float f00 = fetchpix(img, base, x0f, y0f);
    float f10 = fetchpix(img, base, x0f + 1.0f, y0f);
    float f01 = fetchpix(img, base, x0f, y0f + 1.0f);
    float f11 = fetchpix(img, base, x0f + 1.0f, y0f + 1.0f);
    float A  = wy0 * ((wx0 * f00) + (wx1 * f10));
    float Bv = wy1 * ((wx0 * f01) + (wx1 * f11));
    out[base + pix] = A + Bv;
  }
}

extern "C" void kernel_launch(void* const* d_in, const int* in_sizes, int n_in,
                              void* d_out, int out_size, void* d_ws, size_t ws_size,
                              hipStream_t stream) {
  const float* cam  = (const float*)d_in[0];
  const float* hv   = (const float*)d_in[1];
  const float* img  = (const float*)d_in[2];
  const float* camn = (const float*)d_in[3];
  const int* faces  = (const int*)d_in[4];

  const int B = in_sizes[0] / 3;            // 2
  const int N = in_sizes[1] / (3 * B);      // 5120
  const int F = in_sizes[4] / 3;            // 10240
  const int NCHC = (F + RCH - 1) / RCH;     // 40

  char* wsb = (char*)d_ws;
  size_t ofs = 0;
  float* pos = (float*)(wsb + ofs); ofs += (size_t)B * N * 4 * 4;
  float* uv  = (float*)(wsb + ofs); ofs += (size_t)B * N * 2 * 4;
  ofs = (ofs + 255) & ~(size_t)255;
  float4* fh4   = (float4*)(wsb + ofs); ofs += (size_t)B * F * 4 * sizeof(float4);
  float4* fa4   = (float4*)(wsb + ofs); ofs += (size_t)B * F * 2 * sizeof(float4);
  float4* srec  = (float4*)(wsb + ofs); ofs += (size_t)B * F * 4 * sizeof(float4);
  float4* bboxs = (float4*)(wsb + ofs); ofs += (size_t)B * F * sizeof(float4);
  uint* bkt = (uint*)(wsb + ofs); ofs += (size_t)B * F * 4;
  uint* cnt = (uint*)(wsb + ofs); ofs += (size_t)B * K_BUCKETS * 4;
  uint* off = (uint*)(wsb + ofs); ofs += (size_t)B * K_BUCKETS * 4;
  float* lbC = (float*)(wsb + ofs); ofs += (size_t)B * NCHC * 4;

  int nz = B * K_BUCKETS;
  k_zero<<<(nz + 255) / 256, 256, 0, stream>>>(cnt, nz);
  int nv = B * N;
  k_transform<<<(nv + 255) / 256, 256, 0, stream>>>(hv, cam, camn, pos, uv, N, B);
  int nf = B * F;
  k_faces<<<(nf + 255) / 256, 256, 0, stream>>>(faces, pos, uv, fh4, fa4, bkt, cnt, F, N, B);
  k_prefix<<<B, 1024, 0, stream>>>(cnt, off);
  k_scatter<<<(nf + 255) / 256, 256, 0, stream>>>(fh4, bkt, off, srec, bboxs, F, B);
  int nlb = B * NCHC;
  k_lb<<<(nlb + 255) / 256, 256, 0, stream>>>(srec, lbC, F, NCHC, B);
  k_raster<<<B * 256, 256, 0, stream>>>(srec, fa4, bboxs, lbC, img, (float*)d_out, F, NCHC);
}

// Round 6
// 207.747 us; speedup vs baseline: 11.5222x; 5.2861x over previous
//
#include <hip/hip_runtime.h>
#include <stdint.h>

typedef unsigned int uint;
typedef unsigned long long ull;

// B=2, N=5120, F=10240, H=W=256. Bit-exact fp32 replication of the reference
// (contract off, IEEE div). Pipeline:
//   transform -> per-face records -> bucket-sort faces by zmin (4096 buckets)
//   -> raster: grid = (b, 16x16 tile, z-segment). Each block scans its slice
//      of the z-sorted faces in 256-face chunks: ballot-compact bbox hits
//      (pad 0.004) into LDS queue, gather records, branchless per-pixel test,
//      local best = packed u64 (z_bits<<32 | orig_f). Termination per chunk:
//      __syncthreads_and(lb >= min(local_z, polled packed z) + TOL). Merge via
//      device atomicMin on packed (R2-proven). k_sample recomputes the
//      winner's barycentrics bit-identically and does the bilinear sample.
// Winner = lexicographic (z, orig_f) min == reference chunked argmin.
// Record = 4 float4: q0={xmin,xmax,ymin,ymax} q1={v0x,v0y,e1x,e1y}
//                    q2={e2x,e2y,inv,z0}      q3={z1,z2,bits(orig_f),lb}

#define K_BUCKETS 4096
#define ZLO 0.0f
#define ZHI 20.0f
#define TOL 1e-3f
#define RCH 256          // faces per chunk in raster
#define NSEG 8           // z-segments per tile
#define PAD 0.004f       // conservative cull pad (>=100x fp slack)

__device__ __forceinline__ float clip11(float t) {
  return fminf(1.0f, fmaxf(-1.0f, t));
}

__global__ void k_zero(uint* __restrict__ p, int n) {
  int t = blockIdx.x * 256 + threadIdx.x;
  if (t < n) p[t] = 0u;
}

__global__ void k_initpk(ull* __restrict__ p, int n) {
  int t = blockIdx.x * 256 + threadIdx.x;
  if (t < n) p[t] = 0xFFFFFFFFFFFFFFFFull;
}

__global__ void k_transform(const float* __restrict__ hv,
                            const float* __restrict__ cam,
                            const float* __restrict__ camn,
                            float* __restrict__ pos,   // B*N*4
                            float* __restrict__ uv,    // B*N*2
                            int N, int B) {
#pragma clang fp contract(off)
  int t = blockIdx.x * 256 + threadIdx.x;
  if (t >= B * N) return;
  int b = t / N;
  float X0 = hv[t * 3 + 0];
  float X1 = hv[t * 3 + 1];
  float X2 = hv[t * 3 + 2];
  {
    float c0 = camn[b * 3 + 0], c1 = camn[b * 3 + 1], c2 = camn[b * 3 + 2];
    float t0 = c0 * (X0 + c1);
    float t1 = c0 * (X1 + c2);
    float t2 = c0 * X2;
    pos[t * 4 + 0] = clip11(t0);
    pos[t * 4 + 1] = clip11(-t1);
    pos[t * 4 + 2] = -t2 + 10.0f;
    pos[t * 4 + 3] = 0.0f;
  }
  {
    float c0 = cam[b * 3 + 0], c1 = cam[b * 3 + 1], c2 = cam[b * 3 + 2];
    float t0 = c0 * (X0 + c1);
    float t1 = c0 * (X1 + c2);
    uv[t * 2 + 0] = clip11(t0);
    uv[t * 2 + 1] = clip11(-t1);
  }
}

__global__ void k_faces(const int* __restrict__ faces,
                        const float* __restrict__ pos,
                        const float* __restrict__ uv,
                        float4* __restrict__ fh4,   // B*F*4 (orig order)
                        float4* __restrict__ fa4,   // B*F*2 (orig order)
                        uint* __restrict__ bkt,     // B*F
                        uint* __restrict__ cnt,     // B*K
                        int F, int N, int B) {
#pragma clang fp contract(off)
  int t = blockIdx.x * 256 + threadIdx.x;
  if (t >= B * F) return;
  int b = t / F;
  int f = t - b * F;
  int i0 = faces[f * 3 + 0];
  int i1 = faces[f * 3 + 1];
  int i2 = faces[f * 3 + 2];
  const float* p0 = pos + (size_t)(b * N + i0) * 4;
  const float* p1 = pos + (size_t)(b * N + i1) * 4;
  const float* p2 = pos + (size_t)(b * N + i2) * 4;
  float x0 = p0[0], y0 = p0[1], z0 = p0[2];
  float x1 = p1[0], y1 = p1[1], z1 = p1[2];
  float x2 = p2[0], y2 = p2[1], z2 = p2[2];
  float e1x = x1 - x0;
  float e1y = y1 - y0;
  float e2x = x2 - x0;
  float e2y = y2 - y0;
  float d = (e1x * e2y) - (e2x * e1y);
  float inv;
  if (fabsf(d) > 1e-8f) {
    inv = 1.0f / d;                     // IEEE division
  } else {
    inv = __int_as_float(0x7fc00000);   // NaN -> inside test fails
  }
  float4* fq = fh4 + (size_t)t * 4;
  fq[0] = make_float4(fminf(x0, fminf(x1, x2)), fmaxf(x0, fmaxf(x1, x2)),
                      fminf(y0, fminf(y1, y2)), fmaxf(y0, fmaxf(y1, y2)));
  fq[1] = make_float4(x0, y0, e1x, e1y);
  fq[2] = make_float4(e2x, e2y, inv, z0);
  fq[3] = make_float4(z1, z2, 0.0f, 0.0f);

  float zmn = fminf(z0, fminf(z1, z2));
  int kb = (int)((zmn - ZLO) * ((float)K_BUCKETS / (ZHI - ZLO)));
  kb = min(max(kb, 0), K_BUCKETS - 1);
  bkt[t] = (uint)kb;
  atomicAdd(&cnt[b * K_BUCKETS + kb], 1u);

  float u0 = uv[(size_t)(b * N + i0) * 2 + 0];
  float v0 = uv[(size_t)(b * N + i0) * 2 + 1];
  float u1 = uv[(size_t)(b * N + i1) * 2 + 0];
  float v1 = uv[(size_t)(b * N + i1) * 2 + 1];
  float u2 = uv[(size_t)(b * N + i2) * 2 + 0];
  float v2 = uv[(size_t)(b * N + i2) * 2 + 1];
  float4* aq = fa4 + (size_t)t * 2;
  aq[0] = make_float4(u0, v0, u1, v1);
  aq[1] = make_float4(u2, v2, 0.0f, 0.0f);
}

// one block per batch; exclusive prefix over K_BUCKETS counts
__global__ void __launch_bounds__(1024) k_prefix(const uint* __restrict__ cnt,
                                                 uint* __restrict__ off) {
  __shared__ uint s[1024];
  int b = blockIdx.x;
  const uint* c = cnt + (size_t)b * K_BUCKETS;
  uint* o = off + (size_t)b * K_BUCKETS;
  int tid = threadIdx.x;
  uint v0 = c[tid * 4 + 0], v1 = c[tid * 4 + 1], v2 = c[tid * 4 + 2], v3 = c[tid * 4 + 3];
  uint sum = v0 + v1 + v2 + v3;
  s[tid] = sum;
  __syncthreads();
  for (int d = 1; d < 1024; d <<= 1) {
    uint t = (tid >= d) ? s[tid - d] : 0u;
    __syncthreads();
    s[tid] += t;
    __syncthreads();
  }
  uint run = s[tid] - sum;   // exclusive
  o[tid * 4 + 0] = run; run += v0;
  o[tid * 4 + 1] = run; run += v1;
  o[tid * 4 + 2] = run; run += v2;
  o[tid * 4 + 3] = run;
}

__global__ void k_scatter(const float4* __restrict__ fh4,
                          const uint* __restrict__ bkt,
                          uint* __restrict__ off,       // consumed as cursor
                          float4* __restrict__ srec,    // B*F*4 sorted
                          float4* __restrict__ bboxs,   // B*F sorted bboxes
                          int F, int B) {
  int t = blockIdx.x * 256 + threadIdx.x;
  if (t >= B * F) return;
  int b = t / F;
  int f = t - b * F;
  uint kb = bkt[t];
  uint pos = atomicAdd(&off[b * K_BUCKETS + kb], 1u);
  const float4* s = fh4 + (size_t)t * 4;
  float4 q0 = s[0], q1 = s[1], q2 = s[2], q3 = s[3];
  q3.z = __uint_as_float((uint)f);
  q3.w = (kb == 0u) ? -1e30f : (ZLO + (float)kb * ((ZHI - ZLO) / (float)K_BUCKETS));
  float4* d = srec + ((size_t)b * F + pos) * 4;
  d[0] = q0; d[1] = q1; d[2] = q2; d[3] = q3;
  bboxs[(size_t)b * F + pos] = q0;
}

// per-chunk z lower bound: lb of the first sorted face of each RCH-chunk
__global__ void k_lb(const float4* __restrict__ srec,
                     float* __restrict__ lbC,
                     int F, int NCHC, int B) {
  int t = blockIdx.x * 256 + threadIdx.x;
  if (t >= B * NCHC) return;
  int b = t / NCHC;
  int ch = t - b * NCHC;
  int fi = ch * RCH;
  if (fi >= F) { lbC[t] = 1e30f; return; }
  lbC[t] = srec[((size_t)b * F + fi) * 4 + 3].w;
}

// grid = B * 256 tiles * NSEG; block = 256 threads = one 16x16 tile
__global__ void __launch_bounds__(256) k_raster(const float4* __restrict__ srec,
                                                const float4* __restrict__ bboxs,
                                                const float* __restrict__ lbC,
                                                ull* __restrict__ packed,
                                                int F, int NCHC) {
#pragma clang fp contract(off)
  int blk = blockIdx.x;             // ((b*256 + tile)*NSEG + s)
  int s = blk & (NSEG - 1);
  int tile = (blk / NSEG) & 255;
  int b = blk / (NSEG * 256);
  int tx = tile & 15, ty = tile >> 4;
  int tid = threadIdx.x;
  int c = tid & 15, r = tid >> 4;
  int col = tx * 16 + c;
  int row = ty * 16 + r;

  float px = (col + 0.5f) / 256.0f * 2.0f - 1.0f;
  float py = (row + 0.5f) / 256.0f * 2.0f - 1.0f;
  float txlo = (tx * 16 + 0.5f) / 256.0f * 2.0f - 1.0f - PAD;
  float txhi = (tx * 16 + 15.5f) / 256.0f * 2.0f - 1.0f + PAD;
  float tylo = (ty * 16 + 0.5f) / 256.0f * 2.0f - 1.0f - PAD;
  float tyhi = (ty * 16 + 15.5f) / 256.0f * 2.0f - 1.0f + PAD;

  const float4* __restrict__ srecB = srec + (size_t)b * F * 4;
  const float4* __restrict__ bbB = bboxs + (size_t)b * F;
  const float* __restrict__ lbB = lbC + b * NCHC;
  size_t pixidx = ((size_t)b << 16) + (row << 8) + col;

  __shared__ float4 recs[RCH * 4];   // 16 KB
  __shared__ uint qs[RCH];
  __shared__ uint wcnt[4];

  ull best = 0xFFFFFFFFFFFFFFFFull;

  int cps = (NCHC + NSEG - 1) / NSEG;
  int ch0 = s * cps;
  int ch1 = min(NCHC, ch0 + cps);

  for (int ch = ch0; ch < ch1; ++ch) {
    float lb = lbB[ch];
    // termination hint: min(local best z, globally merged z so far).
    // polled value is monotone-decreasing (atomicMin) -> stale reads are
    // only conservative. NaN (no winner yet) makes the predicate false.
    float lz = __uint_as_float((uint)(best >> 32));
    float pz = __uint_as_float((uint)(packed[pixidx] >> 32));
    float known = fminf(lz, pz);   // IEEE minNum: NaN operand is dropped
    if (__syncthreads_and((int)(lb >= known + TOL))) break;

    int cb = ch * RCH;
    int si = cb + tid;
    bool ok = false;
    if (si < F) {
      float4 bb = bbB[si];   // coalesced
      ok = (bb.x <= txhi && bb.y >= txlo && bb.z <= tyhi && bb.w >= tylo);
    }
    ull m = __ballot(ok);
    int lane = tid & 63, wv = tid >> 6;
    if (lane == 0) wcnt[wv] = (uint)__popcll(m);
    int rank = (int)__popcll(m & ((1ull << lane) - 1ull));
    __syncthreads();
    int woff = 0;
#pragma unroll
    for (int w = 0; w < 4; ++w)
      if (w < wv) woff += (int)wcnt[w];
    int nq = (int)(wcnt[0] + wcnt[1] + wcnt[2] + wcnt[3]);
    if (ok) qs[woff + rank] = (uint)si;   // order-preserving (ascending si)
    __syncthreads();
    // cooperative gather of full records (64B per face, L2-resident)
    for (int idx = tid; idx < nq * 4; idx += 256)
      recs[idx] = srecB[(size_t)qs[idx >> 2] * 4 + (idx & 3)];
    __syncthreads();
    // branchless, unrolled: independent LDS broadcasts pipeline
#pragma clang loop unroll_count(4)
    for (int k = 0; k < nq; ++k) {
      float4 q1 = recs[k * 4 + 1];
      float4 q2 = recs[k * 4 + 2];
      float4 q3 = recs[k * 4 + 3];
      float dpx = px - q1.x;
      float dpy = py - q1.y;
      float w1 = (dpx * q2.y - q2.x * dpy) * q2.z;
      float w2 = (q1.z * dpy - dpx * q1.w) * q2.z;
      float w0 = (1.0f - w1) - w2;
      bool inside = (w0 >= 0.0f) && (w1 >= 0.0f) && (w2 >= 0.0f);
      float z = (w0 * q2.w + w1 * q3.x) + w2 * q3.y;
      ull cand = ((ull)__float_as_uint(z) << 32) | (ull)__float_as_uint(q3.z);
      // z > 0 always => float bits monotone => u64 compare is lex (z, orig_f)
      best = (inside && cand < best) ? cand : best;
    }
  }

  if (best != 0xFFFFFFFFFFFFFFFFull)
    atomicMin(packed + pixidx, best);
}

__device__ __forceinline__ float fetchpix(const float* __restrict__ img, int base,
                                          float ixf, float iyf) {
  bool valid = (ixf >= 0.0f) && (ixf < 256.0f) && (iyf >= 0.0f) && (iyf < 256.0f);
  int ix = (int)fminf(255.0f, fmaxf(0.0f, ixf));
  int iy = (int)fminf(255.0f, fmaxf(0.0f, iyf));
  float v = img[base + iy * 256 + ix];
  return valid ? v : 0.0f;
}

__global__ void __launch_bounds__(256) k_sample(const float4* __restrict__ fh4,
                                                const float4* __restrict__ fa4,
                                                const ull* __restrict__ packed,
                                                const float* __restrict__ img,
                                                float* __restrict__ out,
                                                int F) {
#pragma clang fp contract(off)
  int t = blockIdx.x * 256 + threadIdx.x;   // over B*65536
  int b = t >> 16;
  int pix = t & 65535;
  int row = pix >> 8;
  int col = pix & 255;
  float px = (col + 0.5f) / 256.0f * 2.0f - 1.0f;
  float py = (row + 0.5f) / 256.0f * 2.0f - 1.0f;

  ull pk = packed[t];
  uint f = (uint)pk;
  float gx = 0.0f, gy = 0.0f;
  if (f != 0xFFFFFFFFu) {
    const float4* fq = fh4 + ((size_t)b * F + f) * 4;
    float4 q1 = fq[1];
    float4 q2 = fq[2];
    float dpx = px - q1.x;
    float dpy = py - q1.y;
    float w1 = (dpx * q2.y - q2.x * dpy) * q2.z;   // bit-identical to k_raster
    float w2 = (q1.z * dpy - dpx * q1.w) * q2.z;
    float w0 = (1.0f - w1) - w2;
    const float4* aq = fa4 + ((size_t)b * F + f) * 2;
    float4 a0 = aq[0];
    float4 a1 = aq[1];
    gx = (w0 * a0.x + w1 * a0.z) + w2 * a1.x;
    gy = (w0 * a0.y + w1 * a0.w) + w2 * a1.y;
  }

  // grid_sample (align_corners=False, zero pad), exact ref op order
  float x = (gx + 1.0f) * 0.5f * 256.0f - 0.5f;
  float y = (gy + 1.0f) * 0.5f * 256.0f - 0.5f;
  float x0f = floorf(x), y0f = floorf(y);
  float wx1 = x - x0f, wx0 = 1.0f - wx1;
  float wy1 = y - y0f, wy0 = 1.0f - wy1;

  for (int ch = 0; ch < 3; ++ch) {
    int base = (b * 3 + ch) * 65536;
    float f00 = fetchpix(img, base, x0f, y0f);
    float f10 = fetchpix(img, base, x0f + 1.0f, y0f);
    float f01 = fetchpix(img, base, x0f, y0f + 1.0f);
    float f11 = fetchpix(img, base, x0f + 1.0f, y0f + 1.0f);
    float A  = wy0 * ((wx0 * f00) + (wx1 * f10));
    float Bv = wy1 * ((wx0 * f01) + (wx1 * f11));
    out[base + pix] = A + Bv;
  }
}

extern "C" void kernel_launch(void* const* d_in, const int* in_sizes, int n_in,
                              void* d_out, int out_size, void* d_ws, size_t ws_size,
                              hipStream_t stream) {
  const float* cam  = (const float*)d_in[0];
  const float* hv   = (const float*)d_in[1];
  const float* img  = (const float*)d_in[2];
  const float* camn = (const float*)d_in[3];
  const int* faces  = (const int*)d_in[4];

  const int B = in_sizes[0] / 3;            // 2
  const int N = in_sizes[1] / (3 * B);      // 5120
  const int F = in_sizes[4] / 3;            // 10240
  const int NCHC = (F + RCH - 1) / RCH;     // 40
  const int P = 65536;

  char* wsb = (char*)d_ws;
  size_t ofs = 0;
  float* pos = (float*)(wsb + ofs); ofs += (size_t)B * N * 4 * 4;
  float* uv  = (float*)(wsb + ofs); ofs += (size_t)B * N * 2 * 4;
  ofs = (ofs + 255) & ~(size_t)255;
  float4* fh4   = (float4*)(wsb + ofs); ofs += (size_t)B * F * 4 * sizeof(float4);
  float4* fa4   = (float4*)(wsb + ofs); ofs += (size_t)B * F * 2 * sizeof(float4);
  float4* srec  = (float4*)(wsb + ofs); ofs += (size_t)B * F * 4 * sizeof(float4);
  float4* bboxs = (float4*)(wsb + ofs); ofs += (size_t)B * F * sizeof(float4);
  uint* bkt = (uint*)(wsb + ofs); ofs += (size_t)B * F * 4;
  uint* cnt = (uint*)(wsb + ofs); ofs += (size_t)B * K_BUCKETS * 4;
  uint* off = (uint*)(wsb + ofs); ofs += (size_t)B * K_BUCKETS * 4;
  float* lbC = (float*)(wsb + ofs); ofs += (size_t)B * NCHC * 4;
  ofs = (ofs + 255) & ~(size_t)255;
  ull* packed = (ull*)(wsb + ofs); ofs += (size_t)B * P * sizeof(ull);

  int nz = B * K_BUCKETS;
  k_zero<<<(nz + 255) / 256, 256, 0, stream>>>(cnt, nz);
  int np = B * P;
  k_initpk<<<(np + 255) / 256, 256, 0, stream>>>(packed, np);
  int nv = B * N;
  k_transform<<<(nv + 255) / 256, 256, 0, stream>>>(hv, cam, camn, pos, uv, N, B);
  int nf = B * F;
  k_faces<<<(nf + 255) / 256, 256, 0, stream>>>(faces, pos, uv, fh4, fa4, bkt, cnt, F, N, B);
  k_prefix<<<B, 1024, 0, stream>>>(cnt, off);
  k_scatter<<<(nf + 255) / 256, 256, 0, stream>>>(fh4, bkt, off, srec, bboxs, F, B);
  int nlb = B * NCHC;
  k_lb<<<(nlb + 255) / 256, 256, 0, stream>>>(srec, lbC, F, NCHC, B);
  k_raster<<<B * 256 * NSEG, 256, 0, stream>>>(srec, bboxs, lbC, packed, F, NCHC);
  k_sample<<<(np + 255) / 256, 256, 0, stream>>>(fh4, fa4, packed, img, (float*)d_out, F);
}

// Round 7
// 195.027 us; speedup vs baseline: 12.2737x; 1.0652x over previous
//
#include <hip/hip_runtime.h>
#include <stdint.h>

typedef unsigned int uint;
typedef unsigned long long ull;

// B=2, N=5120, F=10240, H=W=256. Bit-exact fp32 replication of the reference
// (contract off, IEEE div). Pipeline:
//   transform -> per-face records -> bucket-sort faces by zmin (4096 buckets)
//   -> raster: grid = (b, 16x16 tile, z-segment). Per 256-face chunk:
//      ballot-compact bbox hits into LDS queue, gather records, branchless
//      per-pixel test, local best = packed u64 (z_bits<<32 | orig_f).
//      Exit when #not-done pixels <= T: enqueue each not-done pixel with its
//      unscanned chunk range [ch, ch1) into a global cleanup queue.
//   -> k_cleanup: one wave per queue entry, 64 lanes split the entry's faces,
//      shfl-reduce the u64 min, atomicMin merge. (kills the border-tile tail)
//   -> k_sample recomputes winner barycentrics bit-identically + bilinear.
// Winner = lexicographic (z, orig_f) min == reference chunked argmin.
// Record = 4 float4: q0={xmin,xmax,ymin,ymax} q1={v0x,v0y,e1x,e1y}
//                    q2={e2x,e2y,inv,z0}      q3={z1,z2,bits(orig_f),lb}

#define K_BUCKETS 4096
#define ZLO 0.0f
#define ZHI 20.0f
#define TOL 1e-3f
#define RCH 256          // faces per chunk in raster
#define NSEG 8           // z-segments per tile
#define PAD 0.004f       // conservative cull pad (>=100x fp slack)
#define TLEFT 48         // max leftover pixels handed to cleanup per exit
#define QCAP (4096 * TLEFT)

__device__ __forceinline__ float clip11(float t) {
  return fminf(1.0f, fmaxf(-1.0f, t));
}

__global__ void k_zero(uint* __restrict__ p, int n) {
  int t = blockIdx.x * 256 + threadIdx.x;
  if (t < n) p[t] = 0u;
}

__global__ void k_initpk(ull* __restrict__ p, int n) {
  int t = blockIdx.x * 256 + threadIdx.x;
  if (t < n) p[t] = 0xFFFFFFFFFFFFFFFFull;
}

__global__ void k_transform(const float* __restrict__ hv,
                            const float* __restrict__ cam,
                            const float* __restrict__ camn,
                            float* __restrict__ pos,   // B*N*4
                            float* __restrict__ uv,    // B*N*2
                            int N, int B) {
#pragma clang fp contract(off)
  int t = blockIdx.x * 256 + threadIdx.x;
  if (t >= B * N) return;
  int b = t / N;
  float X0 = hv[t * 3 + 0];
  float X1 = hv[t * 3 + 1];
  float X2 = hv[t * 3 + 2];
  {
    float c0 = camn[b * 3 + 0], c1 = camn[b * 3 + 1], c2 = camn[b * 3 + 2];
    float t0 = c0 * (X0 + c1);
    float t1 = c0 * (X1 + c2);
    float t2 = c0 * X2;
    pos[t * 4 + 0] = clip11(t0);
    pos[t * 4 + 1] = clip11(-t1);
    pos[t * 4 + 2] = -t2 + 10.0f;
    pos[t * 4 + 3] = 0.0f;
  }
  {
    float c0 = cam[b * 3 + 0], c1 = cam[b * 3 + 1], c2 = cam[b * 3 + 2];
    float t0 = c0 * (X0 + c1);
    float t1 = c0 * (X1 + c2);
    uv[t * 2 + 0] = clip11(t0);
    uv[t * 2 + 1] = clip11(-t1);
  }
}

__global__ void k_faces(const int* __restrict__ faces,
                        const float* __restrict__ pos,
                        const float* __restrict__ uv,
                        float4* __restrict__ fh4,   // B*F*4 (orig order)
                        float4* __restrict__ fa4,   // B*F*2 (orig order)
                        uint* __restrict__ bkt,     // B*F
                        uint* __restrict__ cnt,     // B*K
                        int F, int N, int B) {
#pragma clang fp contract(off)
  int t = blockIdx.x * 256 + threadIdx.x;
  if (t >= B * F) return;
  int b = t / F;
  int f = t - b * F;
  int i0 = faces[f * 3 + 0];
  int i1 = faces[f * 3 + 1];
  int i2 = faces[f * 3 + 2];
  const float* p0 = pos + (size_t)(b * N + i0) * 4;
  const float* p1 = pos + (size_t)(b * N + i1) * 4;
  const float* p2 = pos + (size_t)(b * N + i2) * 4;
  float x0 = p0[0], y0 = p0[1], z0 = p0[2];
  float x1 = p1[0], y1 = p1[1], z1 = p1[2];
  float x2 = p2[0], y2 = p2[1], z2 = p2[2];
  float e1x = x1 - x0;
  float e1y = y1 - y0;
  float e2x = x2 - x0;
  float e2y = y2 - y0;
  float d = (e1x * e2y) - (e2x * e1y);
  float inv;
  if (fabsf(d) > 1e-8f) {
    inv = 1.0f / d;                     // IEEE division
  } else {
    inv = __int_as_float(0x7fc00000);   // NaN -> inside test fails
  }
  float4* fq = fh4 + (size_t)t * 4;
  fq[0] = make_float4(fminf(x0, fminf(x1, x2)), fmaxf(x0, fmaxf(x1, x2)),
                      fminf(y0, fminf(y1, y2)), fmaxf(y0, fmaxf(y1, y2)));
  fq[1] = make_float4(x0, y0, e1x, e1y);
  fq[2] = make_float4(e2x, e2y, inv, z0);
  fq[3] = make_float4(z1, z2, 0.0f, 0.0f);

  float zmn = fminf(z0, fminf(z1, z2));
  int kb = (int)((zmn - ZLO) * ((float)K_BUCKETS / (ZHI - ZLO)));
  kb = min(max(kb, 0), K_BUCKETS - 1);
  bkt[t] = (uint)kb;
  atomicAdd(&cnt[b * K_BUCKETS + kb], 1u);

  float u0 = uv[(size_t)(b * N + i0) * 2 + 0];
  float v0 = uv[(size_t)(b * N + i0) * 2 + 1];
  float u1 = uv[(size_t)(b * N + i1) * 2 + 0];
  float v1 = uv[(size_t)(b * N + i1) * 2 + 1];
  float u2 = uv[(size_t)(b * N + i2) * 2 + 0];
  float v2 = uv[(size_t)(b * N + i2) * 2 + 1];
  float4* aq = fa4 + (size_t)t * 2;
  aq[0] = make_float4(u0, v0, u1, v1);
  aq[1] = make_float4(u2, v2, 0.0f, 0.0f);
}

// one block per batch; exclusive prefix over K_BUCKETS counts
__global__ void __launch_bounds__(1024) k_prefix(const uint* __restrict__ cnt,
                                                 uint* __restrict__ off) {
  __shared__ uint s[1024];
  int b = blockIdx.x;
  const uint* c = cnt + (size_t)b * K_BUCKETS;
  uint* o = off + (size_t)b * K_BUCKETS;
  int tid = threadIdx.x;
  uint v0 = c[tid * 4 + 0], v1 = c[tid * 4 + 1], v2 = c[tid * 4 + 2], v3 = c[tid * 4 + 3];
  uint sum = v0 + v1 + v2 + v3;
  s[tid] = sum;
  __syncthreads();
  for (int d = 1; d < 1024; d <<= 1) {
    uint t = (tid >= d) ? s[tid - d] : 0u;
    __syncthreads();
    s[tid] += t;
    __syncthreads();
  }
  uint run = s[tid] - sum;   // exclusive
  o[tid * 4 + 0] = run; run += v0;
  o[tid * 4 + 1] = run; run += v1;
  o[tid * 4 + 2] = run; run += v2;
  o[tid * 4 + 3] = run;
}

__global__ void k_scatter(const float4* __restrict__ fh4,
                          const uint* __restrict__ bkt,
                          uint* __restrict__ off,       // consumed as cursor
                          float4* __restrict__ srec,    // B*F*4 sorted
                          float4* __restrict__ bboxs,   // B*F sorted bboxes
                          int F, int B) {
  int t = blockIdx.x * 256 + threadIdx.x;
  if (t >= B * F) return;
  int b = t / F;
  int f = t - b * F;
  uint kb = bkt[t];
  uint pos = atomicAdd(&off[b * K_BUCKETS + kb], 1u);
  const float4* s = fh4 + (size_t)t * 4;
  float4 q0 = s[0], q1 = s[1], q2 = s[2], q3 = s[3];
  q3.z = __uint_as_float((uint)f);
  q3.w = (kb == 0u) ? -1e30f : (ZLO + (float)kb * ((ZHI - ZLO) / (float)K_BUCKETS));
  float4* d = srec + ((size_t)b * F + pos) * 4;
  d[0] = q0; d[1] = q1; d[2] = q2; d[3] = q3;
  bboxs[(size_t)b * F + pos] = q0;
}

// per-chunk z lower bound: lb of the first sorted face of each RCH-chunk
__global__ void k_lb(const float4* __restrict__ srec,
                     float* __restrict__ lbC,
                     int F, int NCHC, int B) {
  int t = blockIdx.x * 256 + threadIdx.x;
  if (t >= B * NCHC) return;
  int b = t / NCHC;
  int ch = t - b * NCHC;
  int fi = ch * RCH;
  if (fi >= F) { lbC[t] = 1e30f; return; }
  lbC[t] = srec[((size_t)b * F + fi) * 4 + 3].w;
}

// grid = B * 256 tiles * NSEG; block = 256 threads = one 16x16 tile
__global__ void __launch_bounds__(256) k_raster(const float4* __restrict__ srec,
                                                const float4* __restrict__ bboxs,
                                                const float* __restrict__ lbC,
                                                ull* __restrict__ packed,
                                                uint* __restrict__ qcnt,
                                                uint* __restrict__ queue,
                                                int F, int NCHC) {
#pragma clang fp contract(off)
  int blk = blockIdx.x;             // ((b*256 + tile)*NSEG + s)
  int s = blk & (NSEG - 1);
  int tile = (blk / NSEG) & 255;
  int b = blk / (NSEG * 256);
  int tx = tile & 15, ty = tile >> 4;
  int tid = threadIdx.x;
  int c = tid & 15, r = tid >> 4;
  int col = tx * 16 + c;
  int row = ty * 16 + r;

  float px = (col + 0.5f) / 256.0f * 2.0f - 1.0f;
  float py = (row + 0.5f) / 256.0f * 2.0f - 1.0f;
  float txlo = (tx * 16 + 0.5f) / 256.0f * 2.0f - 1.0f - PAD;
  float txhi = (tx * 16 + 15.5f) / 256.0f * 2.0f - 1.0f + PAD;
  float tylo = (ty * 16 + 0.5f) / 256.0f * 2.0f - 1.0f - PAD;
  float tyhi = (ty * 16 + 15.5f) / 256.0f * 2.0f - 1.0f + PAD;

  const float4* __restrict__ srecB = srec + (size_t)b * F * 4;
  const float4* __restrict__ bbB = bboxs + (size_t)b * F;
  const float* __restrict__ lbB = lbC + b * NCHC;
  size_t pixidx = ((size_t)b << 16) + (row << 8) + col;

  __shared__ float4 recs[RCH * 4];   // 16 KB
  __shared__ uint qs[RCH];
  __shared__ uint wcnt[4];

  ull best = 0xFFFFFFFFFFFFFFFFull;

  int cps = (NCHC + NSEG - 1) / NSEG;
  int ch0 = s * cps;
  int ch1 = min(NCHC, ch0 + cps);

  for (int ch = ch0; ch < ch1; ++ch) {
    float lb = lbB[ch];
    // done = no face in [ch, ch1) can beat the known winner by > fp-slack.
    // known = min(local best z, polled global z). Polled value is
    // monotone-decreasing and a valid upper bound of the final winner even
    // when published by a partially-scanned block. NaN -> not done.
    float lz = __uint_as_float((uint)(best >> 32));
    float pz = __uint_as_float((uint)(packed[pixidx] >> 32));
    float known = fminf(lz, pz);   // IEEE minNum: NaN operand dropped
    bool done = (lb >= known + TOL);
    int notdone = __syncthreads_count((int)(!done));   // full barrier
    if (notdone <= TLEFT) {
      // hand each unfinished pixel (with its unscanned range) to cleanup
      if (!done) {
        uint qi = atomicAdd(qcnt, 1u);
        queue[qi] = (uint)pixidx | ((uint)ch << 17) | ((uint)ch1 << 23);
      }
      break;
    }

    int cb = ch * RCH;
    int si = cb + tid;
    bool ok = false;
    if (si < F) {
      float4 bb = bbB[si];   // coalesced
      ok = (bb.x <= txhi && bb.y >= txlo && bb.z <= tyhi && bb.w >= tylo);
    }
    ull m = __ballot(ok);
    int lane = tid & 63, wv = tid >> 6;
    if (lane == 0) wcnt[wv] = (uint)__popcll(m);
    int rank = (int)__popcll(m & ((1ull << lane) - 1ull));
    __syncthreads();
    int woff = 0;
#pragma unroll
    for (int w = 0; w < 4; ++w)
      if (w < wv) woff += (int)wcnt[w];
    int nq = (int)(wcnt[0] + wcnt[1] + wcnt[2] + wcnt[3]);
    if (ok) qs[woff + rank] = (uint)si;   // order-preserving (ascending si)
    __syncthreads();
    // cooperative gather of full records (64B per face, L2-resident)
    for (int idx = tid; idx < nq * 4; idx += 256)
      recs[idx] = srecB[(size_t)qs[idx >> 2] * 4 + (idx & 3)];
    __syncthreads();
    // branchless, unrolled: independent LDS broadcasts pipeline
#pragma clang loop unroll_count(4)
    for (int k = 0; k < nq; ++k) {
      float4 q1 = recs[k * 4 + 1];
      float4 q2 = recs[k * 4 + 2];
      float4 q3 = recs[k * 4 + 3];
      float dpx = px - q1.x;
      float dpy = py - q1.y;
      float w1 = (dpx * q2.y - q2.x * dpy) * q2.z;
      float w2 = (q1.z * dpy - dpx * q1.w) * q2.z;
      float w0 = (1.0f - w1) - w2;
      bool inside = (w0 >= 0.0f) && (w1 >= 0.0f) && (w2 >= 0.0f);
      float z = (w0 * q2.w + w1 * q3.x) + w2 * q3.y;
      ull cand = ((ull)__float_as_uint(z) << 32) | (ull)__float_as_uint(q3.z);
      // z > 0 always => float bits monotone => u64 compare is lex (z, orig_f)
      best = (inside && cand < best) ? cand : best;
    }
  }

  if (best != 0xFFFFFFFFFFFFFFFFull)
    atomicMin(packed + pixidx, best);
}

// one wave per queue entry: 64 lanes split the entry's [ch0,ch1) face range
__global__ void __launch_bounds__(256) k_cleanup(const float4* __restrict__ srec,
                                                 const uint* __restrict__ queue,
                                                 const uint* __restrict__ qcnt,
                                                 ull* __restrict__ packed,
                                                 int F) {
#pragma clang fp contract(off)
  uint n = *qcnt;
  int wslot = blockIdx.x * 4 + (threadIdx.x >> 6);
  int lane = threadIdx.x & 63;
  int nw = gridDim.x * 4;
  for (uint qi = wslot; qi < n; qi += nw) {
    uint e = queue[qi];
    uint pix = e & 0x1FFFFu;
    int c0 = (int)((e >> 17) & 63u);
    int c1 = (int)((e >> 23) & 63u);
    int b = (int)(pix >> 16);
    int row = (int)((pix >> 8) & 255u);
    int col = (int)(pix & 255u);
    float px = (col + 0.5f) / 256.0f * 2.0f - 1.0f;
    float py = (row + 0.5f) / 256.0f * 2.0f - 1.0f;
    const float4* __restrict__ sb = srec + (size_t)b * F * 4;
    ull best = 0xFFFFFFFFFFFFFFFFull;
    int lo = c0 * RCH, hi = min(c1 * RCH, F);
    for (int si = lo + lane; si < hi; si += 64) {
      float4 q1 = sb[(size_t)si * 4 + 1];
      float4 q2 = sb[(size_t)si * 4 + 2];
      float4 q3 = sb[(size_t)si * 4 + 3];
      float dpx = px - q1.x;
      float dpy = py - q1.y;
      float w1 = (dpx * q2.y - q2.x * dpy) * q2.z;
      float w2 = (q1.z * dpy - dpx * q1.w) * q2.z;
      float w0 = (1.0f - w1) - w2;
      bool inside = (w0 >= 0.0f) && (w1 >= 0.0f) && (w2 >= 0.0f);
      float z = (w0 * q2.w + w1 * q3.x) + w2 * q3.y;
      ull cand = ((ull)__float_as_uint(z) << 32) | (ull)__float_as_uint(q3.z);
      best = (inside && cand < best) ? cand : best;
    }
#pragma unroll
    for (int d = 32; d > 0; d >>= 1) {
      ull o = __shfl_down(best, d);
      best = (o < best) ? o : best;
    }
    if (lane == 0 && best != 0xFFFFFFFFFFFFFFFFull)
      atomicMin(packed + pix, best);
  }
}

__device__ __forceinline__ float fetchpix(const float* __restrict__ img, int base,
                                          float ixf, float iyf) {
  bool valid = (ixf >= 0.0f) && (ixf < 256.0f) && (iyf >= 0.0f) && (iyf < 256.0f);
  int ix = (int)fminf(255.0f, fmaxf(0.0f, ixf));
  int iy = (int)fminf(255.0f, fmaxf(0.0f, iyf));
  float v = img[base + iy * 256 + ix];
  return valid ? v : 0.0f;
}

__global__ void __launch_bounds__(256) k_sample(const float4* __restrict__ fh4,
                                                const float4* __restrict__ fa4,
                                                const ull* __restrict__ packed,
                                                const float* __restrict__ img,
                                                float* __restrict__ out,
                                                int F) {
#pragma clang fp contract(off)
  int t = blockIdx.x * 256 + threadIdx.x;   // over B*65536
  int b = t >> 16;
  int pix = t & 65535;
  int row = pix >> 8;
  int col = pix & 255;
  float px = (col + 0.5f) / 256.0f * 2.0f - 1.0f;
  float py = (row + 0.5f) / 256.0f * 2.0f - 1.0f;

  ull pk = packed[t];
  uint f = (uint)pk;
  float gx = 0.0f, gy = 0.0f;
  if (f != 0xFFFFFFFFu) {
    const float4* fq = fh4 + ((size_t)b * F + f) * 4;
    float4 q1 = fq[1];
    float4 q2 = fq[2];
    float dpx = px - q1.x;
    float dpy = py - q1.y;
    float w1 = (dpx * q2.y - q2.x * dpy) * q2.z;   // bit-identical to k_raster
    float w2 = (q1.z * dpy - dpx * q1.w) * q2.z;
    float w0 = (1.0f - w1) - w2;
    const float4* aq = fa4 + ((size_t)b * F + f) * 2;
    float4 a0 = aq[0];
    float4 a1 = aq[1];
    gx = (w0 * a0.x + w1 * a0.z) + w2 * a1.x;
    gy = (w0 * a0.y + w1 * a0.w) + w2 * a1.y;
  }

  // grid_sample (align_corners=False, zero pad), exact ref op order
  float x = (gx + 1.0f) * 0.5f * 256.0f - 0.5f;
  float y = (gy + 1.0f) * 0.5f * 256.0f - 0.5f;
  float x0f = floorf(x), y0f = floorf(y);
  float wx1 = x - x0f, wx0 = 1.0f - wx1;
  float wy1 = y - y0f, wy0 = 1.0f - wy1;

  for (int ch = 0; ch < 3; ++ch) {
    int base = (b * 3 + ch) * 65536;
    float f00 = fetchpix(img, base, x0f, y0f);
    float f10 = fetchpix(img, base, x0f + 1.0f, y0f);
    float f01 = fetchpix(img, base, x0f, y0f + 1.0f);
    float f11 = fetchpix(img, base, x0f + 1.0f, y0f + 1.0f);
    float A  = wy0 * ((wx0 * f00) + (wx1 * f10));
    float Bv = wy1 * ((wx0 * f01) + (wx1 * f11));
    out[base + pix] = A + Bv;
  }
}

extern "C" void kernel_launch(void* const* d_in, const int* in_sizes, int n_in,
                              void* d_out, int out_size, void* d_ws, size_t ws_size,
                              hipStream_t stream) {
  const float* cam  = (const float*)d_in[0];
  const float* hv   = (const float*)d_in[1];
  const float* img  = (const float*)d_in[2];
  const float* camn = (const float*)d_in[3];
  const int* faces  = (const int*)d_in[4];

  const int B = in_sizes[0] / 3;            // 2
  const int N = in_sizes[1] / (3 * B);      // 5120
  const int F = in_sizes[4] / 3;            // 10240
  const int NCHC = (F + RCH - 1) / RCH;     // 40
  const int P = 65536;

  char* wsb = (char*)d_ws;
  size_t ofs = 0;
  float* pos = (float*)(wsb + ofs); ofs += (size_t)B * N * 4 * 4;
  float* uv  = (float*)(wsb + ofs); ofs += (size_t)B * N * 2 * 4;
  ofs = (ofs + 255) & ~(size_t)255;
  float4* fh4   = (float4*)(wsb + ofs); ofs += (size_t)B * F * 4 * sizeof(float4);
  float4* fa4   = (float4*)(wsb + ofs); ofs += (size_t)B * F * 2 * sizeof(float4);
  float4* srec  = (float4*)(wsb + ofs); ofs += (size_t)B * F * 4 * sizeof(float4);
  float4* bboxs = (float4*)(wsb + ofs); ofs += (size_t)B * F * sizeof(float4);
  uint* bkt = (uint*)(wsb + ofs); ofs += (size_t)B * F * 4;
  uint* cnt = (uint*)(wsb + ofs); ofs += (size_t)B * K_BUCKETS * 4;
  uint* qcnt = (uint*)(wsb + ofs); ofs += 256;   // 1 uint + pad
  uint* off = (uint*)(wsb + ofs); ofs += (size_t)B * K_BUCKETS * 4;
  float* lbC = (float*)(wsb + ofs); ofs += (size_t)B * NCHC * 4;
  ofs = (ofs + 255) & ~(size_t)255;
  ull* packed = (ull*)(wsb + ofs); ofs += (size_t)B * P * sizeof(ull);
  uint* queue = (uint*)(wsb + ofs); ofs += (size_t)QCAP * 4;

  int nz = B * K_BUCKETS + 64;   // cnt + qcnt (contiguous)
  k_zero<<<(nz + 255) / 256, 256, 0, stream>>>(cnt, nz);
  int np = B * P;
  k_initpk<<<(np + 255) / 256, 256, 0, stream>>>(packed, np);
  int nv = B * N;
  k_transform<<<(nv + 255) / 256, 256, 0, stream>>>(hv, cam, camn, pos, uv, N, B);
  int nf = B * F;
  k_faces<<<(nf + 255) / 256, 256, 0, stream>>>(faces, pos, uv, fh4, fa4, bkt, cnt, F, N, B);
  k_prefix<<<B, 1024, 0, stream>>>(cnt, off);
  k_scatter<<<(nf + 255) / 256, 256, 0, stream>>>(fh4, bkt, off, srec, bboxs, F, B);
  int nlb = B * NCHC;
  k_lb<<<(nlb + 255) / 256, 256, 0, stream>>>(srec, lbC, F, NCHC, B);
  k_raster<<<B * 256 * NSEG, 256, 0, stream>>>(srec, bboxs, lbC, packed, qcnt, queue, F, NCHC);
  k_cleanup<<<1024, 256, 0, stream>>>(srec, queue, qcnt, packed, F);
  k_sample<<<(np + 255) / 256, 256, 0, stream>>>(fh4, fa4, packed, img, (float*)d_out, F);
}

// Round 8
// 155.560 us; speedup vs baseline: 15.3876x; 1.2537x over previous
//
#include <hip/hip_runtime.h>
#include <stdint.h>

typedef unsigned int uint;
typedef unsigned long long ull;

// B=2, N=5120, F=10240, H=W=256. Bit-exact fp32 replication of the reference
// (contract off, IEEE div). Pipeline:
//   init(zero cnt + init packed + transform) -> per-face records ->
//   bucket-sort faces by zmin (4096 buckets) ->
//   raster: grid = (seg-major: s, b, 16x16 tile). Per 256-face chunk:
//     per-thread bbox + SAT triangle-vs-padded-tile cull -> ballot-compact ->
//     gather records to LDS -> branchless per-pixel test, best = packed u64
//     (z_bits<<32 | orig_f). After each chunk: publish best via atomicMin
//     (partial min is a valid upper bound). Poll with device-scope atomic
//     load; exit when __syncthreads_and(lb >= known + TOL).
//   -> k_sample recomputes winner barycentrics bit-identically + bilinear.
// Winner = lexicographic (z, orig_f) min == reference chunked argmin.
// Record = 4 float4: q0={xmin,xmax,ymin,ymax} q1={v0x,v0y,e1x,e1y}
//                    q2={e2x,e2y,inv,z0}      q3={z1,z2,bits(orig_f),lb}

#define K_BUCKETS 4096
#define ZLO 0.0f
#define ZHI 20.0f
#define TOL 1e-3f
#define RCH 256          // faces per chunk in raster
#define NSEG 8           // z-segments per tile
#define PAD 0.004f       // conservative cull pad (>=100x fp slack)

__device__ __forceinline__ float clip11(float t) {
  return fminf(1.0f, fmaxf(-1.0f, t));
}

// zero cnt + init packed + transform verts, one launch
__global__ void k_init(const float* __restrict__ hv,
                       const float* __restrict__ cam,
                       const float* __restrict__ camn,
                       uint* __restrict__ cnt, int ncnt,
                       ull* __restrict__ packed, int np,
                       float* __restrict__ pos,   // B*N*4
                       float* __restrict__ uv,    // B*N*2
                       int N, int B) {
#pragma clang fp contract(off)
  int t = blockIdx.x * 256 + threadIdx.x;
  if (t < ncnt) cnt[t] = 0u;
  if (t < np) packed[t] = 0xFFFFFFFFFFFFFFFFull;
  if (t < B * N) {
    int b = t / N;
    float X0 = hv[t * 3 + 0];
    float X1 = hv[t * 3 + 1];
    float X2 = hv[t * 3 + 2];
    {
      float c0 = camn[b * 3 + 0], c1 = camn[b * 3 + 1], c2 = camn[b * 3 + 2];
      float t0 = c0 * (X0 + c1);
      float t1 = c0 * (X1 + c2);
      float t2 = c0 * X2;
      pos[t * 4 + 0] = clip11(t0);
      pos[t * 4 + 1] = clip11(-t1);
      pos[t * 4 + 2] = -t2 + 10.0f;
      pos[t * 4 + 3] = 0.0f;
    }
    {
      float c0 = cam[b * 3 + 0], c1 = cam[b * 3 + 1], c2 = cam[b * 3 + 2];
      float t0 = c0 * (X0 + c1);
      float t1 = c0 * (X1 + c2);
      uv[t * 2 + 0] = clip11(t0);
      uv[t * 2 + 1] = clip11(-t1);
    }
  }
}

__global__ void k_faces(const int* __restrict__ faces,
                        const float* __restrict__ pos,
                        const float* __restrict__ uv,
                        float4* __restrict__ fh4,   // B*F*4 (orig order)
                        float4* __restrict__ fa4,   // B*F*2 (orig order)
                        uint* __restrict__ bkt,     // B*F
                        uint* __restrict__ cnt,     // B*K
                        int F, int N, int B) {
#pragma clang fp contract(off)
  int t = blockIdx.x * 256 + threadIdx.x;
  if (t >= B * F) return;
  int b = t / F;
  int f = t - b * F;
  int i0 = faces[f * 3 + 0];
  int i1 = faces[f * 3 + 1];
  int i2 = faces[f * 3 + 2];
  const float* p0 = pos + (size_t)(b * N + i0) * 4;
  const float* p1 = pos + (size_t)(b * N + i1) * 4;
  const float* p2 = pos + (size_t)(b * N + i2) * 4;
  float x0 = p0[0], y0 = p0[1], z0 = p0[2];
  float x1 = p1[0], y1 = p1[1], z1 = p1[2];
  float x2 = p2[0], y2 = p2[1], z2 = p2[2];
  float e1x = x1 - x0;
  float e1y = y1 - y0;
  float e2x = x2 - x0;
  float e2y = y2 - y0;
  float d = (e1x * e2y) - (e2x * e1y);
  float inv;
  if (fabsf(d) > 1e-8f) {
    inv = 1.0f / d;                     // IEEE division
  } else {
    inv = __int_as_float(0x7fc00000);   // NaN -> inside test fails
  }
  float4* fq = fh4 + (size_t)t * 4;
  fq[0] = make_float4(fminf(x0, fminf(x1, x2)), fmaxf(x0, fmaxf(x1, x2)),
                      fminf(y0, fminf(y1, y2)), fmaxf(y0, fmaxf(y1, y2)));
  fq[1] = make_float4(x0, y0, e1x, e1y);
  fq[2] = make_float4(e2x, e2y, inv, z0);
  fq[3] = make_float4(z1, z2, 0.0f, 0.0f);

  float zmn = fminf(z0, fminf(z1, z2));
  int kb = (int)((zmn - ZLO) * ((float)K_BUCKETS / (ZHI - ZLO)));
  kb = min(max(kb, 0), K_BUCKETS - 1);
  bkt[t] = (uint)kb;
  atomicAdd(&cnt[b * K_BUCKETS + kb], 1u);

  float u0 = uv[(size_t)(b * N + i0) * 2 + 0];
  float v0 = uv[(size_t)(b * N + i0) * 2 + 1];
  float u1 = uv[(size_t)(b * N + i1) * 2 + 0];
  float v1 = uv[(size_t)(b * N + i1) * 2 + 1];
  float u2 = uv[(size_t)(b * N + i2) * 2 + 0];
  float v2 = uv[(size_t)(b * N + i2) * 2 + 1];
  float4* aq = fa4 + (size_t)t * 2;
  aq[0] = make_float4(u0, v0, u1, v1);
  aq[1] = make_float4(u2, v2, 0.0f, 0.0f);
}

// one block per batch; exclusive prefix over K_BUCKETS counts
__global__ void __launch_bounds__(1024) k_prefix(const uint* __restrict__ cnt,
                                                 uint* __restrict__ off) {
  __shared__ uint s[1024];
  int b = blockIdx.x;
  const uint* c = cnt + (size_t)b * K_BUCKETS;
  uint* o = off + (size_t)b * K_BUCKETS;
  int tid = threadIdx.x;
  uint v0 = c[tid * 4 + 0], v1 = c[tid * 4 + 1], v2 = c[tid * 4 + 2], v3 = c[tid * 4 + 3];
  uint sum = v0 + v1 + v2 + v3;
  s[tid] = sum;
  __syncthreads();
  for (int d = 1; d < 1024; d <<= 1) {
    uint t = (tid >= d) ? s[tid - d] : 0u;
    __syncthreads();
    s[tid] += t;
    __syncthreads();
  }
  uint run = s[tid] - sum;   // exclusive
  o[tid * 4 + 0] = run; run += v0;
  o[tid * 4 + 1] = run; run += v1;
  o[tid * 4 + 2] = run; run += v2;
  o[tid * 4 + 3] = run;
}

__global__ void k_scatter(const float4* __restrict__ fh4,
                          const uint* __restrict__ bkt,
                          uint* __restrict__ off,       // consumed as cursor
                          float4* __restrict__ srec,    // B*F*4 sorted
                          float4* __restrict__ bboxs,   // B*F sorted bboxes
                          int F, int B) {
  int t = blockIdx.x * 256 + threadIdx.x;
  if (t >= B * F) return;
  int b = t / F;
  int f = t - b * F;
  uint kb = bkt[t];
  uint pos = atomicAdd(&off[b * K_BUCKETS + kb], 1u);
  const float4* s = fh4 + (size_t)t * 4;
  float4 q0 = s[0], q1 = s[1], q2 = s[2], q3 = s[3];
  q3.z = __uint_as_float((uint)f);
  q3.w = (kb == 0u) ? -1e30f : (ZLO + (float)kb * ((ZHI - ZLO) / (float)K_BUCKETS));
  float4* d = srec + ((size_t)b * F + pos) * 4;
  d[0] = q0; d[1] = q1; d[2] = q2; d[3] = q3;
  bboxs[(size_t)b * F + pos] = q0;
}

// grid (segment-major) = NSEG * B * 256; block = 256 threads = one 16x16 tile
__global__ void __launch_bounds__(256) k_raster(const float4* __restrict__ srec,
                                                const float4* __restrict__ bboxs,
                                                ull* __restrict__ packed,
                                                int F, int NCHC) {
#pragma clang fp contract(off)
  int blk = blockIdx.x;
  int s = blk / 512;                // segment-major: late segs start later
  int rem = blk - s * 512;          // b*256 + tile
  int b = rem >> 8;
  int tile = rem & 255;
  int tx = tile & 15, ty = tile >> 4;
  int tid = threadIdx.x;
  int c = tid & 15, r = tid >> 4;
  int col = tx * 16 + c;
  int row = ty * 16 + r;

  float px = (col + 0.5f) / 256.0f * 2.0f - 1.0f;
  float py = (row + 0.5f) / 256.0f * 2.0f - 1.0f;
  float txlo = (tx * 16 + 0.5f) / 256.0f * 2.0f - 1.0f - PAD;
  float txhi = (tx * 16 + 15.5f) / 256.0f * 2.0f - 1.0f + PAD;
  float tylo = (ty * 16 + 0.5f) / 256.0f * 2.0f - 1.0f - PAD;
  float tyhi = (ty * 16 + 15.5f) / 256.0f * 2.0f - 1.0f + PAD;

  const float4* __restrict__ srecB = srec + (size_t)b * F * 4;
  const float4* __restrict__ bbB = bboxs + (size_t)b * F;
  size_t pixidx = ((size_t)b << 16) + (row << 8) + col;

  __shared__ float4 recs[RCH * 4];   // 16 KB
  __shared__ uint qs[RCH];
  __shared__ uint wcnt[4];

  ull best = 0xFFFFFFFFFFFFFFFFull;

  int cps = (NCHC + NSEG - 1) / NSEG;
  int ch0 = s * cps;
  int ch1 = min(NCHC, ch0 + cps);

  for (int ch = ch0; ch < ch1; ++ch) {
    // lb = zmin lower bound of every face at sorted index >= ch*RCH
    float lb = srecB[(size_t)(ch * RCH) * 4 + 3].w;
    // known = min(local best z, freshly polled global z). Polled value is a
    // valid upper bound of the final winner (partial publishes are mins over
    // subsets). Device-scope atomic load defeats stale per-XCD L2 lines.
    float lz = __uint_as_float((uint)(best >> 32));
    ull pk = __hip_atomic_load(packed + pixidx, __ATOMIC_RELAXED,
                               __HIP_MEMORY_SCOPE_AGENT);
    float pz = __uint_as_float((uint)(pk >> 32));
    float known = fminf(lz, pz);   // IEEE minNum: NaN operand dropped
    bool done = (lb >= known + TOL);
    if (__syncthreads_and((int)done)) break;

    int cb = ch * RCH;
    int si = cb + tid;
    bool ok = false;
    if (si < F) {
      float4 bb = bbB[si];   // coalesced
      ok = (bb.x <= txhi && bb.y >= txlo && bb.z <= tyhi && bb.w >= tylo);
      if (ok) {
        // SAT: separated if all padded-rect corners strictly outside one
        // triangle edge (inward = side of third vertex). Conservative:
        // NaN (degenerate) keeps the face; inner test rejects it.
        float4 q1 = srecB[(size_t)si * 4 + 1];   // v0x v0y e1x e1y
        float4 q2 = srecB[(size_t)si * 4 + 2];   // e2x e2y inv z0
        float ax = q1.x, ay = q1.y;
        float e1x = q1.z, e1y = q1.w;
        float e2x = q2.x, e2y = q2.y;
        float sg = q2.z;                          // sign(d) carrier (inv)
        float e3x = e2x - e1x, e3y = e2y - e1y;
        float bxx = ax + e1x, bxy = ay + e1y;
        // edge v0->v1, normal toward v2
        float nx = -sg * e1y, ny = sg * e1x;
        float dotA = nx * ((nx > 0.0f ? txhi : txlo) - ax) +
                     ny * ((ny > 0.0f ? tyhi : tylo) - ay);
        // edge v0->v2, normal toward v1
        nx = sg * e2y; ny = -sg * e2x;
        float dotB = nx * ((nx > 0.0f ? txhi : txlo) - ax) +
                     ny * ((ny > 0.0f ? tyhi : tylo) - ay);
        // edge v1->v2, normal toward v0
        nx = -sg * e3y; ny = sg * e3x;
        float dotC = nx * ((nx > 0.0f ? txhi : txlo) - bxx) +
                     ny * ((ny > 0.0f ? tyhi : tylo) - bxy);
        ok = !(dotA < 0.0f) && !(dotB < 0.0f) && !(dotC < 0.0f);
      }
    }
    ull m = __ballot(ok);
    int lane = tid & 63, wv = tid >> 6;
    if (lane == 0) wcnt[wv] = (uint)__popcll(m);
    int rank = (int)__popcll(m & ((1ull << lane) - 1ull));
    __syncthreads();
    int woff = 0;
#pragma unroll
    for (int w = 0; w < 4; ++w)
      if (w < wv) woff += (int)wcnt[w];
    int nq = (int)(wcnt[0] + wcnt[1] + wcnt[2] + wcnt[3]);
    if (ok) qs[woff + rank] = (uint)si;   // order-preserving (ascending si)
    __syncthreads();
    // cooperative gather of full records (64B per face, L2-resident)
    for (int idx = tid; idx < nq * 4; idx += 256)
      recs[idx] = srecB[(size_t)qs[idx >> 2] * 4 + (idx & 3)];
    __syncthreads();
    // branchless, unrolled: independent LDS broadcasts pipeline
#pragma clang loop unroll_count(4)
    for (int k = 0; k < nq; ++k) {
      float4 q1 = recs[k * 4 + 1];
      float4 q2 = recs[k * 4 + 2];
      float4 q3 = recs[k * 4 + 3];
      float dpx = px - q1.x;
      float dpy = py - q1.y;
      float w1 = (dpx * q2.y - q2.x * dpy) * q2.z;
      float w2 = (q1.z * dpy - dpx * q1.w) * q2.z;
      float w0 = (1.0f - w1) - w2;
      bool inside = (w0 >= 0.0f) && (w1 >= 0.0f) && (w2 >= 0.0f);
      float z = (w0 * q2.w + w1 * q3.x) + w2 * q3.y;
      ull cand = ((ull)__float_as_uint(z) << 32) | (ull)__float_as_uint(q3.z);
      // z > 0 always => float bits monotone => u64 compare is lex (z, orig_f)
      best = (inside && cand < best) ? cand : best;
    }
    // publish partial best so sibling segments can terminate early
    if (best != 0xFFFFFFFFFFFFFFFFull)
      atomicMin(packed + pixidx, best);
  }

  if (best != 0xFFFFFFFFFFFFFFFFull)
    atomicMin(packed + pixidx, best);
}

__device__ __forceinline__ float fetchpix(const float* __restrict__ img, int base,
                                          float ixf, float iyf) {
  bool valid = (ixf >= 0.0f) && (ixf < 256.0f) && (iyf >= 0.0f) && (iyf < 256.0f);
  int ix = (int)fminf(255.0f, fmaxf(0.0f, ixf));
  int iy = (int)fminf(255.0f, fmaxf(0.0f, iyf));
  float v = img[base + iy * 256 + ix];
  return valid ? v : 0.0f;
}

__global__ void __launch_bounds__(256) k_sample(const float4* __restrict__ fh4,
                                                const float4* __restrict__ fa4,
                                                const ull* __restrict__ packed,
                                                const float* __restrict__ img,
                                                float* __restrict__ out,
                                                int F) {
#pragma clang fp contract(off)
  int t = blockIdx.x * 256 + threadIdx.x;   // over B*65536
  int b = t >> 16;
  int pix = t & 65535;
  int row = pix >> 8;
  int col = pix & 255;
  float px = (col + 0.5f) / 256.0f * 2.0f - 1.0f;
  float py = (row + 0.5f) / 256.0f * 2.0f - 1.0f;

  ull pk = packed[t];
  uint f = (uint)pk;
  float gx = 0.0f, gy = 0.0f;
  if (f != 0xFFFFFFFFu) {
    const float4* fq = fh4 + ((size_t)b * F + f) * 4;
    float4 q1 = fq[1];
    float4 q2 = fq[2];
    float dpx = px - q1.x;
    float dpy = py - q1.y;
    float w1 = (dpx * q2.y - q2.x * dpy) * q2.z;   // bit-identical to k_raster
    float w2 = (q1.z * dpy - dpx * q1.w) * q2.z;
    float w0 = (1.0f - w1) - w2;
    const float4* aq = fa4 + ((size_t)b * F + f) * 2;
    float4 a0 = aq[0];
    float4 a1 = aq[1];
    gx = (w0 * a0.x + w1 * a0.z) + w2 * a1.x;
    gy = (w0 * a0.y + w1 * a0.w) + w2 * a1.y;
  }

  // grid_sample (align_corners=False, zero pad), exact ref op order
  float x = (gx + 1.0f) * 0.5f * 256.0f - 0.5f;
  float y = (gy + 1.0f) * 0.5f * 256.0f - 0.5f;
  float x0f = floorf(x), y0f = floorf(y);
  float wx1 = x - x0f, wx0 = 1.0f - wx1;
  float wy1 = y - y0f, wy0 = 1.0f - wy1;

  for (int ch = 0; ch < 3; ++ch) {
    int base = (b * 3 + ch) * 65536;
    float f00 = fetchpix(img, base, x0f, y0f);
    float f10 = fetchpix(img, base, x0f + 1.0f, y0f);
    float f01 = fetchpix(img, base, x0f, y0f + 1.0f);
    float f11 = fetchpix(img, base, x0f + 1.0f, y0f + 1.0f);
    float A  = wy0 * ((wx0 * f00) + (wx1 * f10));
    float Bv = wy1 * ((wx0 * f01) + (wx1 * f11));
    out[base + pix] = A + Bv;
  }
}

extern "C" void kernel_launch(void* const* d_in, const int* in_sizes, int n_in,
                              void* d_out, int out_size, void* d_ws, size_t ws_size,
                              hipStream_t stream) {
  const float* cam  = (const float*)d_in[0];
  const float* hv   = (const float*)d_in[1];
  const float* img  = (const float*)d_in[2];
  const float* camn = (const float*)d_in[3];
  const int* faces  = (const int*)d_in[4];

  const int B = in_sizes[0] / 3;            // 2
  const int N = in_sizes[1] / (3 * B);      // 5120
  const int F = in_sizes[4] / 3;            // 10240
  const int NCHC = (F + RCH - 1) / RCH;     // 40
  const int P = 65536;

  char* wsb = (char*)d_ws;
  size_t ofs = 0;
  float* pos = (float*)(wsb + ofs); ofs += (size_t)B * N * 4 * 4;
  float* uv  = (float*)(wsb + ofs); ofs += (size_t)B * N * 2 * 4;
  ofs = (ofs + 255) & ~(size_t)255;
  float4* fh4   = (float4*)(wsb + ofs); ofs += (size_t)B * F * 4 * sizeof(float4);
  float4* fa4   = (float4*)(wsb + ofs); ofs += (size_t)B * F * 2 * sizeof(float4);
  float4* srec  = (float4*)(wsb + ofs); ofs += (size_t)B * F * 4 * sizeof(float4);
  float4* bboxs = (float4*)(wsb + ofs); ofs += (size_t)B * F * sizeof(float4);
  uint* bkt = (uint*)(wsb + ofs); ofs += (size_t)B * F * 4;
  uint* cnt = (uint*)(wsb + ofs); ofs += (size_t)B * K_BUCKETS * 4;
  uint* off = (uint*)(wsb + ofs); ofs += (size_t)B * K_BUCKETS * 4;
  ofs = (ofs + 255) & ~(size_t)255;
  ull* packed = (ull*)(wsb + ofs); ofs += (size_t)B * P * sizeof(ull);

  int np = B * P;
  int ncnt = B * K_BUCKETS;
  k_init<<<(np + 255) / 256, 256, 0, stream>>>(hv, cam, camn, cnt, ncnt,
                                               packed, np, pos, uv, N, B);
  int nf = B * F;
  k_faces<<<(nf + 255) / 256, 256, 0, stream>>>(faces, pos, uv, fh4, fa4, bkt, cnt, F, N, B);
  k_prefix<<<B, 1024, 0, stream>>>(cnt, off);
  k_scatter<<<(nf + 255) / 256, 256, 0, stream>>>(fh4, bkt, off, srec, bboxs, F, B);
  k_raster<<<NSEG * B * 256, 256, 0, stream>>>(srec, bboxs, packed, F, NCHC);
  k_sample<<<(np + 255) / 256, 256, 0, stream>>>(fh4, fa4, packed, img, (float*)d_out, F);
}